// Round 3
// 827.975 us; speedup vs baseline: 1.0409x; 1.0409x over previous
//
#include <hip/hip_runtime.h>
#include <stdint.h>

#define BB 8
#define NN 4096
#define CC 64
#define MM 1024
#define EE (BB*MM)   // 8192 centroids
#define KK 64        // max neighbors
#define F3 256       // output channels
#define SM 104       // msg LDS stride (elements), 16B-aligned rows (208 B)
#define SH 136       // h LDS stride (elements), 16B-aligned rows (272 B)
#define CAP 768      // candidate buffer

typedef __bf16 bf16x8 __attribute__((ext_vector_type(8)));
typedef float floatx4 __attribute__((ext_vector_type(4)));

// ---- wave64 reductions via DPP (VALU latency, no LDS) ----
#define DPP_MAXSTEP(ctrl, rmask) { \
    unsigned o = (unsigned)__builtin_amdgcn_update_dpp(0, (int)v, ctrl, rmask, 0xf, false); \
    v = v > o ? v : o; }
__device__ __forceinline__ unsigned wave_umax_u32(unsigned v) {
  DPP_MAXSTEP(0x111, 0xf)
  DPP_MAXSTEP(0x112, 0xf)
  DPP_MAXSTEP(0x114, 0xf)
  DPP_MAXSTEP(0x118, 0xf)
  DPP_MAXSTEP(0x142, 0xa)
  DPP_MAXSTEP(0x143, 0xc)
  return (unsigned)__builtin_amdgcn_readlane((int)v, 63);
}
#define DPP_MINSTEP(ctrl, rmask) { \
    unsigned o = (unsigned)__builtin_amdgcn_update_dpp((int)0xffffffffu, (int)v, ctrl, rmask, 0xf, false); \
    v = v < o ? v : o; }
__device__ __forceinline__ unsigned wave_umin_u32(unsigned v) {
  DPP_MINSTEP(0x111, 0xf)
  DPP_MINSTEP(0x112, 0xf)
  DPP_MINSTEP(0x114, 0xf)
  DPP_MINSTEP(0x118, 0xf)
  DPP_MINSTEP(0x142, 0xa)
  DPP_MINSTEP(0x143, 0xc)
  return (unsigned)__builtin_amdgcn_readlane((int)v, 63);
}

// ---- FPS (blocks 0..7, 4 waves) + W transpose (8..247) + pos->float4 (248..375) ----
// 4 waves per FPS block: inner distance work is work-conserving across wave
// partitions (4096 pts spread over 4 SIMDs either way), but per-wave DPP
// reduction overhead and cross-wave fan-in halve vs the 8-wave version.
// Index reduction: always the exact 6-step DPP umin (round-0-verified path;
// no divergent branch, no dynamic-index readlane).
__global__ __launch_bounds__(256) void fps_prep_kernel(
    const float* __restrict__ pos,
    const float* __restrict__ W1, const float* __restrict__ W2, const float* __restrict__ W3,
    int* __restrict__ fpsIdx, float* __restrict__ ctr,
    __bf16* __restrict__ W1t, __bf16* __restrict__ W2t, __bf16* __restrict__ W3t,
    float4* __restrict__ pos4) {
  __shared__ float4 sP4[NN];                       // 64 KB
  __shared__ unsigned long long sRed[2][4];
  const int blk = blockIdx.x;
  const int t = threadIdx.x;

  if (blk >= BB) {
    if (blk < 248) {                               // wprep: 61440 elements, 240 blocks
      const int i0 = (blk - 8) * 256 + t;
      if (i0 < 128 * 96) {
        const int n = i0 / 96, k = i0 % 96;
        W1t[i0] = (k < 67) ? (__bf16)W1[k * 128 + n] : (__bf16)0.0f;
      } else if (i0 < 128 * 96 + 128 * 128) {
        const int i = i0 - 128 * 96;
        const int n = i / 128, k = i % 128;
        W2t[i] = (__bf16)W2[k * 128 + n];
      } else {
        const int i = i0 - (128 * 96 + 128 * 128);
        const int n = i / 128, k = i % 128;
        W3t[i] = (__bf16)W3[k * 256 + n];
      }
    } else {                                       // posp: 32768 points, 128 blocks
      const int i = (blk - 248) * 256 + t;
      pos4[i] = make_float4(pos[(long)i * 3 + 0], pos[(long)i * 3 + 1],
                            pos[(long)i * 3 + 2], 0.0f);
    }
    return;
  }

  const int g = blk;
  const int lane = t & 63, wv = t >> 6;            // 4 waves
  float px[16], py[16], pz[16], mind[16];
#pragma unroll
  for (int j = 0; j < 16; ++j) {
    const int p = t + (j << 8);
    const long base = ((long)g * NN + p) * 3;
    px[j] = pos[base + 0];
    py[j] = pos[base + 1];
    pz[j] = pos[base + 2];
    mind[j] = 1e10f;
    sP4[p] = make_float4(px[j], py[j], pz[j], 0.0f);
  }
  __syncthreads();
  float wx = sP4[0].x, wy = sP4[0].y, wz = sP4[0].z;
  int win0 = 0, win1 = 0, win2 = 0, win3 = 0;      // static regs, no dynamic idx
  for (int s = 1; s < MM; ++s) {
    // --- inner: update min-dist and track per-thread argmax (exact ref numerics) ---
    unsigned bb = 0u, bidx = (unsigned)t;
#pragma unroll
    for (int j = 0; j < 16; ++j) {
      const float dx = __fsub_rn(px[j], wx);
      const float dy = __fsub_rn(py[j], wy);
      const float dz = __fsub_rn(pz[j], wz);
      const float d2 = __fadd_rn(__fadd_rn(__fmul_rn(dx, dx), __fmul_rn(dy, dy)), __fmul_rn(dz, dz));
      mind[j] = fminf(mind[j], d2);
      const unsigned mb = __float_as_uint(mind[j]);   // positive floats: bit order == value order
      if (mb > bb) { bb = mb; bidx = (unsigned)(t + (j << 8)); }  // strict >: smallest j on tie
    }
    // --- wave max (6-step DPP) + exact min-index among tied lanes ---
    const unsigned maxv = wave_umax_u32(bb);
    const unsigned cand = (bb == maxv) ? bidx : 0xffffffffu;
    const unsigned widx_w = wave_umin_u32(cand);
    // --- cross-wave exchange: 4 slots, double-buffered (one barrier per iter) ---
    if (lane == 0)
      sRed[s & 1][wv] = ((unsigned long long)maxv << 32) | (unsigned long long)(~widx_w);
    __syncthreads();
    unsigned long long m = sRed[s & 1][0];
#pragma unroll
    for (int w = 1; w < 4; ++w) {
      const unsigned long long o = sRed[s & 1][w];
      m = o > m ? o : m;
    }
    const int widx = (int)(~(unsigned)m);
    const float4 wp = sP4[widx];
    wx = wp.x; wy = wp.y; wz = wp.z;
    win0 = (s == t)       ? widx : win0;
    win1 = (s == t + 256) ? widx : win1;
    win2 = (s == t + 512) ? widx : win2;
    win3 = (s == t + 768) ? widx : win3;
  }
  {
    const long e0 = (long)g * MM + t;
    const float4 p0 = sP4[win0];
    fpsIdx[e0] = win0;
    ctr[e0 * 3 + 0] = p0.x; ctr[e0 * 3 + 1] = p0.y; ctr[e0 * 3 + 2] = p0.z;
    const long e1 = e0 + 256;
    const float4 p1 = sP4[win1];
    fpsIdx[e1] = win1;
    ctr[e1 * 3 + 0] = p1.x; ctr[e1 * 3 + 1] = p1.y; ctr[e1 * 3 + 2] = p1.z;
    const long e2 = e0 + 512;
    const float4 p2 = sP4[win2];
    fpsIdx[e2] = win2;
    ctr[e2 * 3 + 0] = p2.x; ctr[e2 * 3 + 1] = p2.y; ctr[e2 * 3 + 2] = p2.z;
    const long e3 = e0 + 768;
    const float4 p3 = sP4[win3];
    fpsIdx[e3] = win3;
    ctr[e3 * 3 + 0] = p3.x; ctr[e3 * 3 + 1] = p3.y; ctr[e3 * 3 + 2] = p3.z;
  }
}

// ---- Fused radius-search + rank-top-K + gather + 3-layer MLP (MFMA) + masked max ----
// One block (512 thr = 8 waves) per centroid; tail outputs folded in.
__global__ __launch_bounds__(512) void mlp_kernel(const float* __restrict__ x,
    const float4* __restrict__ pos4, const float* __restrict__ ctr,
    const int* __restrict__ fpsIdx,
    const __bf16* __restrict__ W1t, const __bf16* __restrict__ W2t,
    const __bf16* __restrict__ W3t,
    const float* __restrict__ b1, const float* __restrict__ b2,
    const float* __restrict__ b3,
    float* __restrict__ outX, float* __restrict__ outP,
    float* __restrict__ outB, float* __restrict__ outS) {
  __shared__ __align__(16) __bf16 sMsg[64 * SM];   // 13312 B; overlays sDI (6144 B)
  __shared__ __align__(16) __bf16 sH[64 * SH];     // 17408 B
  __shared__ int sSel[KK];
  __shared__ int sCnt;
  unsigned long long* sDI = (unsigned long long*)sMsg;  // [CAP] packed (d2bits<<32 | idx)

  const int e = blockIdx.x;
  const int t = threadIdx.x;
  const int b = e >> 10;
  const int lane = t & 63, wv = t >> 6;

  if (t == 0) sCnt = 0;
  const float cx = ctr[(long)e * 3 + 0];
  const float cy = ctr[(long)e * 3 + 1];
  const float cz = ctr[(long)e * 3 + 2];
  if (t < 3) outP[(long)e * 3 + t] = ctr[(long)e * 3 + t];
  if (t == 3) { outB[e] = (float)b; outS[e] = (float)(b * NN + fpsIdx[e]); }
  const float R2 = (float)(0.2 * 0.2);
  __syncthreads();

  // Phase A: scan 4096 points (float4 loads); ballot-compact candidates to LDS.
#pragma unroll
  for (int q = 0; q < NN / 512; ++q) {
    const int p = t + q * 512;
    const float4 P = pos4[b * NN + p];
    const float dx = __fsub_rn(cx, P.x);
    const float dy = __fsub_rn(cy, P.y);
    const float dz = __fsub_rn(cz, P.z);
    const float d2 = __fadd_rn(__fadd_rn(__fmul_rn(dx, dx), __fmul_rn(dy, dy)), __fmul_rn(dz, dz));
    const bool v = d2 < R2;
    const unsigned long long mask = __ballot(v);
    int wbase = 0;
    if (lane == 0 && mask) wbase = atomicAdd(&sCnt, (int)__popcll(mask));
    wbase = __shfl(wbase, 0);
    if (v) {
      const int off = wbase + (int)__popcll(mask & ((1ull << lane) - 1ull));
      if (off < CAP)
        sDI[off] = ((unsigned long long)__float_as_uint(d2) << 32) | (unsigned)p;
    }
  }
  __syncthreads();
  int cnt = sCnt; cnt = cnt > CAP ? CAP : cnt;
  const int nsel = cnt < KK ? cnt : KK;

  // Phase B: parallel rank selection. rank(i) = #{j : key_j < key_i}; keep rank<K.
  for (int i = t; i < cnt; i += 512) {
    const unsigned long long my = sDI[i];
    int rank = 0;
#pragma unroll 8
    for (int j = 0; j < cnt; ++j) rank += (sDI[j] < my) ? 1 : 0;
    if (rank < KK) sSel[rank] = (int)(unsigned)(my & 0xffffffffu);
  }
  __syncthreads();   // sDI dead from here; sMsg may be written
  cnt = nsel;

  // Phase C: stage msg tile [64 x (64 feat | 3 dpos | zero-pad)] into LDS as bf16.
  {
    const int r = t >> 3, p = t & 7;
    float4 a = make_float4(0.f, 0.f, 0.f, 0.f), c4 = a;
    if (r < cnt) {
      const float* xr = x + (long)(b * NN + sSel[r]) * CC + p * 8;
      a  = *(const float4*)xr;
      c4 = *(const float4*)(xr + 4);
    }
    __bf16 o[8] = {(__bf16)a.x, (__bf16)a.y, (__bf16)a.z, (__bf16)a.w,
                   (__bf16)c4.x, (__bf16)c4.y, (__bf16)c4.z, (__bf16)c4.w};
    *(uint4*)&sMsg[r * SM + p * 8] = *(uint4*)o;
  }
  if (t < 64) {
    const int r = t;
    __bf16 d0 = (__bf16)0.0f, d1 = (__bf16)0.0f, d2v = (__bf16)0.0f;
    if (r < cnt) {
      const float4 P = pos4[b * NN + sSel[r]];
      d0  = (__bf16)__fsub_rn(P.x, cx);
      d1  = (__bf16)__fsub_rn(P.y, cy);
      d2v = (__bf16)__fsub_rn(P.z, cz);
    }
    sMsg[r * SM + 64] = d0;
    sMsg[r * SM + 65] = d1;
    sMsg[r * SM + 66] = d2v;
    for (int c = 67; c < SM; ++c) sMsg[r * SM + c] = (__bf16)0.0f;
  }
  __syncthreads();

  const int l15 = lane & 15, quad = lane >> 4;
  // ---- layer 1: [64 x 96] @ [96 x 128] -> sH; wave wv owns n-tile wv ----
  {
    floatx4 acc[4] = {};
    const __bf16* wrow = W1t + (wv * 16 + l15) * 96;
#pragma unroll
    for (int ks = 0; ks < 3; ++ks) {
      const bf16x8 bfrag = *(const bf16x8*)(wrow + ks * 32 + quad * 8);
#pragma unroll
      for (int mt = 0; mt < 4; ++mt) {
        const bf16x8 afrag = *(const bf16x8*)&sMsg[(mt * 16 + l15) * SM + ks * 32 + quad * 8];
        acc[mt] = __builtin_amdgcn_mfma_f32_16x16x32_bf16(afrag, bfrag, acc[mt], 0, 0, 0);
      }
    }
    const int col = wv * 16 + l15;
    const float bias = b1[col];
#pragma unroll
    for (int mt = 0; mt < 4; ++mt)
#pragma unroll
      for (int rg = 0; rg < 4; ++rg) {
        const int row = mt * 16 + quad * 4 + rg;
        float v = acc[mt][rg] + bias;
        v = v > 0.0f ? v : 0.0f;
        sH[row * SH + col] = (__bf16)v;
      }
  }
  __syncthreads();
  // ---- layer 2: [64 x 128] @ [128 x 128], IN PLACE on sH ----
  {
    floatx4 acc[4] = {};
    const __bf16* wrow = W2t + (wv * 16 + l15) * 128;
#pragma unroll
    for (int ks = 0; ks < 4; ++ks) {
      const bf16x8 bfrag = *(const bf16x8*)(wrow + ks * 32 + quad * 8);
#pragma unroll
      for (int mt = 0; mt < 4; ++mt) {
        const bf16x8 afrag = *(const bf16x8*)&sH[(mt * 16 + l15) * SH + ks * 32 + quad * 8];
        acc[mt] = __builtin_amdgcn_mfma_f32_16x16x32_bf16(afrag, bfrag, acc[mt], 0, 0, 0);
      }
    }
    __syncthreads();
    const int col = wv * 16 + l15;
    const float bias = b2[col];
#pragma unroll
    for (int mt = 0; mt < 4; ++mt)
#pragma unroll
      for (int rg = 0; rg < 4; ++rg) {
        const int row = mt * 16 + quad * 4 + rg;
        float v = acc[mt][rg] + bias;
        v = v > 0.0f ? v : 0.0f;
        sH[row * SH + col] = (__bf16)v;
      }
  }
  __syncthreads();
  // ---- layer 3: [64 x 128] @ [128 x 256]; wave owns 2 n-tiles; fused masked max ----
  {
    floatx4 acc[2][4] = {};
#pragma unroll
    for (int ks = 0; ks < 4; ++ks) {
      bf16x8 afrag[4];
#pragma unroll
      for (int mt = 0; mt < 4; ++mt)
        afrag[mt] = *(const bf16x8*)&sH[(mt * 16 + l15) * SH + ks * 32 + quad * 8];
#pragma unroll
      for (int i = 0; i < 2; ++i) {
        const bf16x8 bfrag = *(const bf16x8*)(W3t + ((wv * 2 + i) * 16 + l15) * 128 + ks * 32 + quad * 8);
#pragma unroll
        for (int mt = 0; mt < 4; ++mt)
          acc[i][mt] = __builtin_amdgcn_mfma_f32_16x16x32_bf16(afrag[mt], bfrag, acc[i][mt], 0, 0, 0);
      }
    }
#pragma unroll
    for (int i = 0; i < 2; ++i) {
      const int col = (wv * 2 + i) * 16 + l15;
      const float bias = b3[col];
      float mx = 0.0f;  // centroid itself always in-radius => cnt>=1; ReLU >= 0
#pragma unroll
      for (int mt = 0; mt < 4; ++mt)
#pragma unroll
        for (int rg = 0; rg < 4; ++rg) {
          const int row = mt * 16 + quad * 4 + rg;
          float v = acc[i][mt][rg] + bias;
          v = v > 0.0f ? v : 0.0f;
          if (row < cnt) mx = fmaxf(mx, v);
        }
      mx = fmaxf(mx, __shfl_xor(mx, 16));
      mx = fmaxf(mx, __shfl_xor(mx, 32));
      if (quad == 0) outX[(long)e * F3 + col] = mx;
    }
  }
}

extern "C" void kernel_launch(void* const* d_in, const int* in_sizes, int n_in,
                              void* d_out, int out_size, void* d_ws, size_t ws_size,
                              hipStream_t stream) {
  const float* x   = (const float*)d_in[0];
  const float* pos = (const float*)d_in[1];
  const float* W1  = (const float*)d_in[4];
  const float* b1  = (const float*)d_in[5];
  const float* W2  = (const float*)d_in[6];
  const float* b2  = (const float*)d_in[7];
  const float* W3  = (const float*)d_in[8];
  const float* b3  = (const float*)d_in[9];

  // Workspace layout (~778 KB)
  char* ws = (char*)d_ws;
  int*    fpsIdx = (int*)(ws);                 // 8192*4        = 32768
  float*  ctr    = (float*)(ws + 32768);       // 8192*3*4      = 98304   (ends 131072)
  __bf16* W1t    = (__bf16*)(ws + 131072);     // 128*96*2      = 24576   (ends 155648)
  __bf16* W2t    = (__bf16*)(ws + 155648);     // 128*128*2     = 32768   (ends 188416)
  __bf16* W3t    = (__bf16*)(ws + 188416);     // 256*128*2     = 65536   (ends 253952)
  float4* pos4   = (float4*)(ws + 253952);     // 32768*16      = 524288  (ends 778240)

  float* outX = (float*)d_out;                 // [8192,256]
  float* outP = outX + (long)EE * F3;          // [8192,3]
  float* outB = outP + (long)EE * 3;           // [8192]
  float* outS = outB + EE;                     // [8192]

  // blocks: 8 FPS + 240 wprep + 128 posp (256 threads each)
  fps_prep_kernel<<<376, 256, 0, stream>>>(pos, W1, W2, W3,
                                           fpsIdx, ctr, W1t, W2t, W3t, pos4);
  mlp_kernel<<<EE, 512, 0, stream>>>(x, pos4, ctr, fpsIdx, W1t, W2t, W3t,
                                     b1, b2, b3, outX, outP, outB, outS);
}